// Round 6
// baseline (695.402 us; speedup 1.0000x reference)
//
#include <hip/hip_runtime.h>
#include <cstdint>
#include <cstddef>

typedef unsigned short ushort;
typedef unsigned int uint;
typedef __attribute__((ext_vector_type(8))) short short8;
typedef __attribute__((ext_vector_type(8))) unsigned short ushort8;
typedef __attribute__((ext_vector_type(4))) float float4v;

#define DM    2048
#define INNERC 4096
#define LSEQ  4096
#define NBATCH 2
#define MROWS 8192      // NBATCH*LSEQ
#define NHH   64
#define HDD   64
#define NCHUNK 32
#define CHLEN  128

__device__ __forceinline__ float bf2f(ushort u) {
    return __uint_as_float(((unsigned int)u) << 16);
}
__device__ __forceinline__ ushort f2bf(float f) {
    unsigned int u = __float_as_uint(f);
    unsigned int r = u + 0x7FFFu + ((u >> 16) & 1u);
    return (ushort)(r >> 16);
}

// async global->LDS 16B copy. LDS dest must be wave-uniform base + lane*16.
__device__ __forceinline__ void async_cp16(const ushort* __restrict__ g, ushort* l) {
    __builtin_amdgcn_global_load_lds(
        (const __attribute__((address_space(1))) unsigned int*)g,
        (__attribute__((address_space(3))) unsigned int*)l,
        16, 0, 0);
}

// ---------------- diagnostic ----------------
__global__ void diag_kernel(float* __restrict__ out, float val) {
    if (threadIdx.x == 0 && blockIdx.x == 0) out[0] = val;
}

// ---------------- f32 -> bf16 cast (single range) ----------------
__global__ __launch_bounds__(256) void cast_bf16_kernel(
    const float* __restrict__ in, ushort* __restrict__ out, int n) {
    const int i = (blockIdx.x * 256 + threadIdx.x) * 8;
    if (i + 8 > n) return;
    const float4v a = *(const float4v*)(in + i);
    const float4v b = *(const float4v*)(in + i + 4);
    ushort8 o;
    o[0] = f2bf(a[0]); o[1] = f2bf(a[1]); o[2] = f2bf(a[2]); o[3] = f2bf(a[3]);
    o[4] = f2bf(b[0]); o[5] = f2bf(b[1]); o[6] = f2bf(b[2]); o[7] = f2bf(b[3]);
    *(ushort8*)(out + i) = o;
}

// ---------------- f32 -> bf16 cast (two ranges in one launch) ----------------
__global__ __launch_bounds__(256) void cast2_bf16_kernel(
    const float* __restrict__ in1, ushort* __restrict__ out1, int n1,
    const float* __restrict__ in2, ushort* __restrict__ out2, int n2) {
    int i = (blockIdx.x * 256 + threadIdx.x) * 8;
    const float* in;
    ushort* out;
    if (i < n1) {
        in = in1 + i; out = out1 + i;
    } else {
        const int j = i - n1;
        if (j + 8 > n2) return;
        in = in2 + j; out = out2 + j;
    }
    const float4v a = *(const float4v*)(in);
    const float4v b = *(const float4v*)(in + 4);
    ushort8 o;
    o[0] = f2bf(a[0]); o[1] = f2bf(a[1]); o[2] = f2bf(a[2]); o[3] = f2bf(a[3]);
    o[4] = f2bf(b[0]); o[5] = f2bf(b[1]); o[6] = f2bf(b[2]); o[7] = f2bf(b[3]);
    *(ushort8*)(out) = o;
}

// ---------------- bf16 bt-GEMM, 256x256 tile, 8-phase counted-vmcnt ----------
// Out(M,N) = A(M,K) * W(N,K)^T.  512 threads = 8 waves (2M x 4N); per-wave
// output 128x64 -> acc[8][4].  LDS 128 KiB (2 dbuf x (A 32K + B 32K)).
// Granule swizzle: 16B granule (row, q) at slot row*8 + (q ^ (row&7)).
// ds_read addrs = base-reg + compile-time imm (XOR decomposed); staging via
// 4 per-thread 32-bit offsets advanced +64 elems/use; last iteration peeled.
// NO blanket s_waitcnt lgkmcnt(0) after the opening barrier — the compiler
// inserts fine-grained lgkmcnt(N) before each dependent MFMA, so early MFMAs
// start while later ds_reads drain.  Race-safety: every ds_read in a phase
// is consumed by that phase's MFMA, so all reads complete before the last
// MFMA issues, which precedes the closing barrier; hence no wave can see a
// later phase's DMA overwrite a region still being read.
// Gates unchanged: vmcnt(4)@p4, vmcnt(8)@p8 (counted, never 0 in main loop).
// EPI: 0 bf16, 1 sigmoid(acc)*Aux -> bf16 (in-place ok), 2 f32.

#define PH_PRE() __builtin_amdgcn_s_barrier()
#define PH_POST() __builtin_amdgcn_s_barrier()

#define MFMA_Q(AF, RBASE, CL) do { \
    __builtin_amdgcn_s_setprio(1); \
    _Pragma("unroll") for (int kk = 0; kk < 2; ++kk) \
    _Pragma("unroll") for (int rm = 0; rm < 4; ++rm) \
    _Pragma("unroll") for (int cn = 0; cn < 2; ++cn) \
        acc[(RBASE) + rm][(CL) + cn] = __builtin_amdgcn_mfma_f32_16x16x32_bf16( \
            AF[rm][kk], bf[(CL) + cn][kk], acc[(RBASE) + rm][(CL) + cn], 0, 0, 0); \
    __builtin_amdgcn_s_setprio(0); } while (0)

#define READ_A(DST, BUF, HB) do { \
    _Pragma("unroll") for (int rm = 0; rm < 4; ++rm) { \
        DST[rm][0] = *(const short8*)&As[BUF][offA_k0 + ((HB) * 4 + rm) * 1024]; \
        DST[rm][1] = *(const short8*)&As[BUF][offA_k1 + ((HB) * 4 + rm) * 1024]; \
    } } while (0)

#define READ_B2(BUF, CNLO) do { \
    _Pragma("unroll") for (int cn = 0; cn < 2; ++cn) { \
        bf[(CNLO) + cn][0] = *(const short8*)&Bs[BUF][offB_k0 + ((CNLO) + cn) * 1024]; \
        bf[(CNLO) + cn][1] = *(const short8*)&Bs[BUF][offB_k1 + ((CNLO) + cn) * 1024]; \
    } } while (0)

#define STAGE(G, OFF, LBASE) do { \
    async_cp16((G) + (OFF),       (LBASE) + (tid << 3)); \
    async_cp16((G) + (OFF) + k64, (LBASE) + (tid << 3) + 4096); \
    (OFF) += 64; } while (0)

template <int EPI>
__global__ __launch_bounds__(512, 2) void gemm256(
    const ushort* __restrict__ Ab, const ushort* __restrict__ Wb,
    void* __restrict__ Out, const ushort* __restrict__ Aux,
    int M, int N, int K) {
    __shared__ ushort As[2][16384];
    __shared__ ushort Bs[2][16384];

    const int tid  = threadIdx.x;
    const int lane = tid & 63;
    const int w    = tid >> 6;
    const int wm   = w >> 2;          // 0..1
    const int wn   = w & 3;           // 0..3
    const int l15  = lane & 15;
    const int l4   = lane >> 4;       // 0..3
    const int swz7 = l15 & 7;
    const int s01  = swz7 & 3;
    const int b2   = (swz7 >> 2) & 1;

    // XCD-aware block swizzle (nwg divisible by 8 for all our shapes)
    const int gx   = gridDim.x;
    const int nwg  = gx * gridDim.y;
    const int orig = blockIdx.y * gx + blockIdx.x;
    const int swz  = (orig & 7) * (nwg >> 3) + (orig >> 3);
    const int row0 = (swz / gx) * 256;
    const int col0 = (swz % gx) * 256;

    const int ni = K >> 7;            // iterations (2 K-tiles each)

    // precomputed LDS read base offsets (elem units)
    const int commA   = (wm * 128 + l15) * 64 + (l4 ^ s01) * 8;
    const int offA_k0 = commA + (b2 ? 32 : 0);
    const int offA_k1 = commA + (b2 ? 0 : 32);
    const int commB   = (wn * 64 + l15) * 64 + (l4 ^ s01) * 8;
    const int offB_k0 = commB + (b2 ? 32 : 0);
    const int offB_k1 = commB + (b2 ? 0 : 32);

    // precomputed per-thread staging source offsets (elem units)
    const uint rr8 = (uint)(tid >> 3);
    const uint kg8 = (uint)(((tid & 7) ^ ((tid >> 3) & 7)) * 8);
    const uint k64 = (uint)64 * (uint)K;            // 64-row stride (j=1)
    uint oA0 = (uint)(row0) * (uint)K + rr8 * (uint)K + kg8;
    uint oA1 = oA0 + (uint)128 * (uint)K;
    uint oW0 = (uint)(col0) * (uint)K + rr8 * (uint)K + kg8;
    uint oW1 = oW0 + (uint)128 * (uint)K;

    float4v acc[8][4];
#pragma unroll
    for (int i2 = 0; i2 < 8; i2++)
#pragma unroll
        for (int j2 = 0; j2 < 4; j2++) {
            float4v z = {0.f, 0.f, 0.f, 0.f};
            acc[i2][j2] = z;
        }

    short8 afL[4][2], afH[4][2], bf[4][2];

    // -------- prologue: tiles 0 (buf0) and 1 (buf1); wait tile0
    STAGE(Ab, oA0, &As[0][0]);
    STAGE(Ab, oA1, &As[0][8192]);
    STAGE(Wb, oW0, &Bs[0][0]);
    STAGE(Wb, oW1, &Bs[0][8192]);
    STAGE(Ab, oA0, &As[1][0]);
    STAGE(Ab, oA1, &As[1][8192]);
    STAGE(Wb, oW0, &Bs[1][0]);
    STAGE(Wb, oW1, &Bs[1][8192]);
    asm volatile("s_waitcnt vmcnt(8)" ::: "memory");   // tile0 landed
    __builtin_amdgcn_s_barrier();

#pragma unroll 1
    for (int i = 0; i < ni - 1; ++i) {
        // ---- p1: buf0, Q(rm0-3, cn0-1); 12 ds_reads
        READ_A(afL, 0, 0);
        READ_B2(0, 0);
        asm volatile("s_waitcnt lgkmcnt(8)");
        PH_PRE();
        MFMA_Q(afL, 0, 0);
        PH_POST();

        // ---- p2: Q(rm0-3, cn2-3)
        READ_B2(0, 2);
        PH_PRE();
        MFMA_Q(afL, 0, 2);
        PH_POST();

        // ---- p3: Q(rm4-7, cn2-3); stage (u+2).Bh0
        READ_A(afH, 0, 1);
        STAGE(Wb, oW0, &Bs[0][0]);
        PH_PRE();
        MFMA_Q(afH, 4, 2);
        PH_POST();

        // ---- p4: Q(rm4-7, cn0-1); stage (u+2).Bh1; gate buf1 (tile u+1)
        STAGE(Wb, oW1, &Bs[0][8192]);
        PH_PRE();
        MFMA_Q(afH, 4, 0);
        asm volatile("s_waitcnt vmcnt(4)" ::: "memory");
        __builtin_amdgcn_s_barrier();

        // ---- p5: buf1, Q(rm0-3, cn0-1); stage (u+2).Ah0
        READ_A(afL, 1, 0);
        READ_B2(1, 0);
        STAGE(Ab, oA0, &As[0][0]);
        asm volatile("s_waitcnt lgkmcnt(8)");
        PH_PRE();
        MFMA_Q(afL, 0, 0);
        PH_POST();

        // ---- p6: Q(rm0-3, cn2-3); stage (u+2).Ah1
        READ_B2(1, 2);
        STAGE(Ab, oA1, &As[0][8192]);
        PH_PRE();
        MFMA_Q(afL, 0, 2);
        PH_POST();

        // ---- p7: Q(rm4-7, cn2-3); stage (u+3).Bh0+Bh1
        READ_A(afH, 1, 1);
        STAGE(Wb, oW0, &Bs[1][0]);
        STAGE(Wb, oW1, &Bs[1][8192]);
        PH_PRE();
        MFMA_Q(afH, 4, 2);
        PH_POST();

        // ---- p8: Q(rm4-7, cn0-1); stage (u+3).Ah0+Ah1; gate buf0 (tile u+2)
        STAGE(Ab, oA0, &As[1][0]);
        STAGE(Ab, oA1, &As[1][8192]);
        PH_PRE();
        MFMA_Q(afH, 4, 0);
        asm volatile("s_waitcnt vmcnt(8)" ::: "memory");
        __builtin_amdgcn_s_barrier();
    }

    // -------- peeled last iteration: no stages, no intra-phase barriers
    {
        READ_A(afL, 0, 0);
        READ_B2(0, 0);
        READ_B2(0, 2);
        READ_A(afH, 0, 1);
        __builtin_amdgcn_s_setprio(1);
        MFMA_Q(afL, 0, 0);
        MFMA_Q(afL, 0, 2);
        MFMA_Q(afH, 4, 2);
        MFMA_Q(afH, 4, 0);
        __builtin_amdgcn_s_setprio(0);
        asm volatile("s_waitcnt vmcnt(0)" ::: "memory");
        __builtin_amdgcn_s_barrier();
        READ_A(afL, 1, 0);
        READ_B2(1, 0);
        READ_B2(1, 2);
        READ_A(afH, 1, 1);
        __builtin_amdgcn_s_setprio(1);
        MFMA_Q(afL, 0, 0);
        MFMA_Q(afL, 0, 2);
        MFMA_Q(afH, 4, 2);
        MFMA_Q(afH, 4, 0);
        __builtin_amdgcn_s_setprio(0);
    }

    // epilogue: C/D layout col = lane&15, row = (lane>>4)*4 + reg
#pragma unroll
    for (int rm = 0; rm < 8; ++rm) {
#pragma unroll
        for (int cn = 0; cn < 4; ++cn) {
            const int r0 = row0 + wm * 128 + rm * 16 + l4 * 4;
            const int cc = col0 + wn * 64 + cn * 16 + l15;
#pragma unroll
            for (int rr = 0; rr < 4; ++rr) {
                const float v = acc[rm][cn][rr];
                const size_t off = (size_t)(r0 + rr) * N + cc;
                if (EPI == 0) {
                    ((ushort*)Out)[off] = f2bf(v);
                } else if (EPI == 1) {
                    const float g = 1.0f / (1.0f + __expf(-v));
                    ((ushort*)Out)[off] = f2bf(g * bf2f(Aux[off]));
                } else {
                    ((float*)Out)[off] = v;
                }
            }
        }
    }
}

// ---------------- fused conv(K=4)+SiLU+dt+chunk-scan (pass1) ----------------
// Block: 1 chunk (128 rows) x 256 channels; 256 threads, 1 channel/thread.
// One head per wave (64 ch): dt row-reduce = 6 shfl_xor, all lanes get sum.
// Writes X (bf16), dt (f32), and per-chunk scan aggregates sumP/sumS.
// Scan uses bf16-rounded X (matches pass3's re-read semantics).
#define CSCH 256
__global__ __launch_bounds__(256) void conv_scan1_kernel(
    const ushort* __restrict__ proj, const float* __restrict__ cw,
    const float* __restrict__ cb, const float* __restrict__ dtw,
    const float* __restrict__ dtb, const float* __restrict__ A_log,
    const float* __restrict__ Bv, ushort* __restrict__ X,
    float* __restrict__ dt, float* __restrict__ sumP,
    float* __restrict__ sumS) {
    const int blk   = blockIdx.x;              // 1024 = 16 slices * 64 chunks
    const int slice = blk & 15;
    const int chunk = blk >> 4;                // 0..63
    const int b     = chunk >> 5;
    const int chk   = chunk & 31;
    const int bl0   = b * LSEQ + chk * CHLEN;
    const int c     = slice * CSCH + threadIdx.x;   // absolute channel
    const int h     = c >> 6;
    const int p     = c & 63;
    const int lane  = threadIdx.x & 63;

    const float4v wv   = *(const float4v*)(cw + (size_t)c * 4);
    const float biasv  = cb[c];
    const float dtwv   = dtw[c];
    const float dtbv   = dtb[h];
    const float Ac     = -__expf(A_log[c]);    // A_log[h*64+p] == A_log[c]
    const float Bc     = Bv[c];

    const size_t base = (size_t)bl0 * INNERC + c;
    float f0, f1, f2;
    if (chk == 0) {
        f0 = 0.f; f1 = 0.f; f2 = 0.f;
    } else {
        f0 = bf2f(proj[base - 3 * (size_t)INNERC]);
        f1 = bf2f(proj[base - 2 * (size_t)INNERC]);
        f2 = bf2f(proj[base - 1 * (size_t)INNERC]);
    }

    float Pr = 1.0f, s = 0.0f;
#pragma unroll 4
    for (int r = 0; r < CHLEN; ++r) {
        const float fc = bf2f(proj[base + (size_t)r * INNERC]);
        const float a4 = biasv + wv[0] * f0 + wv[1] * f1 + wv[2] * f2 + wv[3] * fc;
        const float sl = a4 / (1.0f + __expf(-a4));   // silu
        const ushort xb = f2bf(sl);
        X[base + (size_t)r * INNERC] = xb;
        // dt: full-wave (=one head) reduction of sl*dtw
        float d = sl * dtwv;
        d += __shfl_xor(d, 1, 64);
        d += __shfl_xor(d, 2, 64);
        d += __shfl_xor(d, 4, 64);
        d += __shfl_xor(d, 8, 64);
        d += __shfl_xor(d, 16, 64);
        d += __shfl_xor(d, 32, 64);
        const float z   = d + dtbv;
        const float dtv = (z > 20.0f) ? z : __logf(1.0f + __expf(z));
        if (lane == 0) dt[(bl0 + r) * 64 + h] = dtv;
        // chunk-local scan with bf16-rounded x
        const float xr = bf2f(xb);
        const float aa = __expf(dtv * Ac);
        Pr *= aa;
        s = aa * s + dtv * Bc * xr;
        f0 = f1; f1 = f2; f2 = fc;
    }
    const size_t task = (size_t)((b * 64 + h) * 32 + chk);
    sumP[task * 64 + p] = Pr;
    sumS[task * 64 + p] = s;
}

// ---------------- chunked diagonal scan, passes 2/3 ----------------
__global__ __launch_bounds__(64) void scan_pass2(
    const float* __restrict__ sumP, const float* __restrict__ sumS,
    float* __restrict__ carry) {
    const int bh = blockIdx.x;
    const int p  = threadIdx.x;
    float c = 0.0f;
    for (int ch = 0; ch < NCHUNK; ch++) {
        const size_t idx = ((size_t)bh * NCHUNK + ch) * 64 + p;
        carry[idx] = c;
        c = sumP[idx] * c + sumS[idx];
    }
}

__global__ __launch_bounds__(256) void scan_pass3(
    const ushort* __restrict__ X, const float* __restrict__ dt,
    const float* __restrict__ carry,
    const float* __restrict__ A_log, const float* __restrict__ Bv,
    const float* __restrict__ Cv, const float* __restrict__ Dv,
    ushort* __restrict__ Y) {
    const int task = blockIdx.x * 4 + (threadIdx.x >> 6);
    const int p  = threadIdx.x & 63;
    const int ch = task & (NCHUNK - 1);
    const int bh = task >> 5;
    const int h  = bh & 63;
    const int b  = bh >> 6;
    const float Ac = -__expf(A_log[h * 64 + p]);
    const float Bc = Bv[h * 64 + p];
    const float Cc = Cv[h * 64 + p];
    const float Dc = Dv[h * 64 + p];
    float s = carry[(size_t)task * 64 + p];
    const int bl0 = b * LSEQ + ch * CHLEN;
#pragma unroll 2
    for (int i = 0; i < CHLEN; i++) {
        const int bl = bl0 + i;
        const size_t xoff = (size_t)bl * INNERC + h * 64 + p;
        const float dtv = dt[bl * 64 + h];
        const float x   = bf2f(X[xoff]);
        const float a   = __expf(dtv * Ac);
        s = a * s + dtv * Bc * x;
        Y[xoff] = f2bf(Cc * s + Dc * x);
    }
}

// ---------------- workspace layout (bytes) ----------------
#define OFF_PROJ  ((size_t)0)            // 67,108,864 : proj -> Y -> comb
#define OFF_HID   ((size_t)67108864)     // 33,554,432 : hidden bf16
#define OFF_WB    ((size_t)100663296)    // 16,777,216 : weight bf16 (reused 3x)
#define OFF_DT    ((size_t)117440512)    //  2,097,152
#define OFF_SUMP  ((size_t)119537664)    //  1,048,576
#define OFF_SUMS  ((size_t)120586240)    //  1,048,576
#define OFF_CARRY ((size_t)121634816)    //  1,048,576
#define WS_NEEDED ((size_t)122683392)    // = 117 MiB

extern "C" void kernel_launch(void* const* d_in, const int* in_sizes, int n_in,
                              void* d_out, int out_size, void* d_ws, size_t ws_size,
                              hipStream_t stream) {
    if (ws_size < WS_NEEDED) {
        diag_kernel<<<1, 64, 0, stream>>>((float*)d_out, (float)(ws_size >> 20));
        return;
    }
    const float* hidden = (const float*)d_in[0];
    const float* w_in   = (const float*)d_in[1];
    const float* w_gate = (const float*)d_in[2];
    const float* w_out  = (const float*)d_in[3];
    const float* conv_w = (const float*)d_in[4];
    const float* conv_b = (const float*)d_in[5];
    const float* dt_w   = (const float*)d_in[6];
    const float* dt_b   = (const float*)d_in[7];
    const float* A_log  = (const float*)d_in[8];
    const float* Bv     = (const float*)d_in[9];
    const float* Cv     = (const float*)d_in[10];
    const float* Dv     = (const float*)d_in[11];

    char* ws = (char*)d_ws;
    ushort* projbuf = (ushort*)(ws + OFF_PROJ);   // proj, then Y, then comb
    ushort* hid16   = (ushort*)(ws + OFF_HID);
    ushort* wbuf    = (ushort*)(ws + OFF_WB);
    float*  dtf     = (float*)(ws + OFF_DT);
    float*  sumP    = (float*)(ws + OFF_SUMP);
    float*  sumS    = (float*)(ws + OFF_SUMS);
    float*  carry   = (float*)(ws + OFF_CARRY);
    ushort* x16     = (ushort*)d_out;             // X scratch inside d_out

    // hidden + in_proj weight casts in one launch
    cast2_bf16_kernel<<<12288, 256, 0, stream>>>(
        hidden, hid16, MROWS * DM, w_in, wbuf, INNERC * DM);

    // in_proj GEMM -> proj (bf16)
    gemm256<0><<<dim3(INNERC / 256, MROWS / 256), 512, 0, stream>>>(
        hid16, wbuf, projbuf, nullptr, MROWS, INNERC, DM);

    // fused conv+silu+dt+chunk-scan -> X (in d_out), dt, sumP/sumS
    conv_scan1_kernel<<<(INNERC / CSCH) * (NBATCH * NCHUNK), 256, 0, stream>>>(
        projbuf, conv_w, conv_b, dt_w, dt_b, A_log, Bv, x16, dtf, sumP, sumS);

    // cross-chunk carries; pass3 writes y into projbuf (proj dead after conv)
    scan_pass2<<<NBATCH * NHH, 64, 0, stream>>>(sumP, sumS, carry);
    scan_pass3<<<(NBATCH * NHH * NCHUNK) / 4, 256, 0, stream>>>(
        x16, dtf, carry, A_log, Bv, Cv, Dv, projbuf);

    // gate GEMM with fused gating: comb = sigmoid(G) * Y, in-place in projbuf
    cast_bf16_kernel<<<4096, 256, 0, stream>>>(w_gate, wbuf, INNERC * DM);
    gemm256<1><<<dim3(INNERC / 256, MROWS / 256), 512, 0, stream>>>(
        hid16, wbuf, projbuf, projbuf, MROWS, INNERC, DM);

    // output projection (f32 out) — overwrites X scratch in d_out
    cast_bf16_kernel<<<4096, 256, 0, stream>>>(w_out, wbuf, DM * INNERC);
    gemm256<2><<<dim3(DM / 256, MROWS / 256), 512, 0, stream>>>(
        projbuf, wbuf, d_out, nullptr, MROWS, DM, INNERC);
}